// Round 5
// baseline (85569.135 us; speedup 1.0000x reference)
//
#include <hip/hip_runtime.h>
#include <math.h>

// ---- model dims ----
#define LAYERS 8
#define WIN    32
#define NH     8
#define DHD    64
#define DM     512
#define DFF    2048
#define NCLS   256
#define MEL    80
#define TT     512

// ---- persistent kernel: 256 blocks x 256 threads (1 block/CU) ----
#define GRID   256
#define BLK    256

// KV history row: 1024 data floats + 32 pad floats (one 128B line) so a
// depth-1 next-line prefetch can never pull an unwritten future row.
#define KVROW  1056

typedef unsigned int  u32;
typedef unsigned long long u64;

// ---- wave=64 reductions ----
__device__ inline float wredsum(float v){
#pragma unroll
  for (int m = 32; m >= 1; m >>= 1) v += __shfl_xor(v, m, 64);
  return v;
}
__device__ inline float wredmax(float v){
#pragma unroll
  for (int m = 32; m >= 1; m >>= 1) v = fmaxf(v, __shfl_xor(v, m, 64));
  return v;
}

// ---- coherent (sc-bit) comm ops: relaxed agent scope ----
__device__ inline float ld_sc(float* p){
  return __hip_atomic_load(p, __ATOMIC_RELAXED, __HIP_MEMORY_SCOPE_AGENT);
}
__device__ inline void st_sc(float* p, float v){
  __hip_atomic_store(p, v, __ATOMIC_RELAXED, __HIP_MEMORY_SCOPE_AGENT);
}
__device__ inline float2 ld_sc2(float* p){
  u64 u = __hip_atomic_load((u64*)p, __ATOMIC_RELAXED, __HIP_MEMORY_SCOPE_AGENT);
  union { u64 u; float2 f; } cv; cv.u = u; return cv.f;
}

// dot(row512_in_LDS, vec512_in_LDS) across one wave
__device__ inline float dot512(const float* w, const float* vec, int lane){
  float4 a0 = *(const float4*)(w + 4*lane);
  float4 a1 = *(const float4*)(w + 256 + 4*lane);
  float4 b0 = *(const float4*)(vec + 4*lane);
  float4 b1 = *(const float4*)(vec + 256 + 4*lane);
  float p = a0.x*b0.x + a0.y*b0.y + a0.z*b0.z + a0.w*b0.w
          + a1.x*b1.x + a1.y*b1.y + a1.z*b1.z + a1.w*b1.w;
  return wredsum(p);
}

__device__ inline float gelu_tanh(float x){
  float x3 = x*x*x;
  return 0.5f*x*(1.0f + tanhf(0.7978845608028654f*(x + 0.044715f*x3)));
}

// ---- split-phase barrier: u32 flags spread over 8 cache lines ----
// Role split (measured: VALUBusy 5.3%, phases ~4.2us — poll and prefetch were
// serialized because the poll's atomic loads drain vmcnt(0), stalling on the
// prefetch's outstanding loads): wave 0 ONLY polls; waves 1-3 ONLY prefetch.
// Their latencies now overlap on independent waves of the same CU.
__device__ inline void bar_arrive(u32* flags, int b, int ph){
  __syncthreads();   // drains vmcnt: all sc stores/atomics of this block visible
  if (threadIdx.x == 0)
    __hip_atomic_store(flags + b, (u32)ph, __ATOMIC_RELAXED, __HIP_MEMORY_SCOPE_AGENT);
}
__device__ inline void bar_wait(u32* flags, int ph){
  int tid = threadIdx.x;
  if (tid < 64){
    u64* fp = (u64*)flags + 2*tid;    // lane i watches flags[4i..4i+4)
    for (;;){
      u64 v0 = __hip_atomic_load(fp,     __ATOMIC_RELAXED, __HIP_MEMORY_SCOPE_AGENT);
      u64 v1 = __hip_atomic_load(fp + 1, __ATOMIC_RELAXED, __HIP_MEMORY_SCOPE_AGENT);
      u32 a0 = (u32)v0, a1 = (u32)(v0 >> 32);
      u32 a2 = (u32)v1, a3 = (u32)(v1 >> 32);
      if (min(min(a0, a1), min(a2, a3)) >= (u32)ph) break;
      __builtin_amdgcn_s_sleep(2);
    }
  }
  asm volatile("" ::: "memory");
  __syncthreads();
}

// fused single-pass LN over 512 els in LDS (src -> dst), stats via sum+sumsq
// in ONE interleaved reduction round. Caller must __syncthreads() after.
__device__ inline void layernorm512(const float* __restrict__ src,
                                    float* __restrict__ dst,
                                    const float* __restrict__ w,
                                    const float* __restrict__ bb,
                                    int tid, int lane, int wid,
                                    float* s_red, float* s_red2){
  float a = src[tid], c = src[tid + 256];
  float p1 = a + c;
  float p2 = a*a + c*c;
#pragma unroll
  for (int m = 32; m >= 1; m >>= 1){
    p1 += __shfl_xor(p1, m, 64);
    p2 += __shfl_xor(p2, m, 64);
  }
  if (lane == 0){ s_red[wid] = p1; s_red2[wid] = p2; }
  __syncthreads();
  float mu  = (s_red[0]+s_red[1]+s_red[2]+s_red[3])   * (1.0f/512.0f);
  float ex2 = (s_red2[0]+s_red2[1]+s_red2[2]+s_red2[3]) * (1.0f/512.0f);
  float var = fmaxf(ex2 - mu*mu, 0.0f);           // guard tiny negative
  float rsig = 1.0f / sqrtf(var + 1e-5f);
  dst[tid]       = (a - mu)*rsig*w[tid]       + bb[tid];
  dst[tid + 256] = (c - mu)*rsig*w[tid + 256] + bb[tid + 256];
}

// float4 global->LDS copy on waves 1-3 only (wave 0 is the barrier poller)
__device__ inline void pf_copy192(const float* __restrict__ g, float* l, int n4){
  if (threadIdx.x < 64) return;
  const float4* g4 = (const float4*)g;
  float4* l4 = (float4*)l;
  for (int i = (int)threadIdx.x - 64; i < n4; i += 192) l4[i] = g4[i];
}

// prefetch this block's 6 kv/q rows for layer l into s_wA (waves 1-3 only)
__device__ inline void pf_kvq192(const float* kv_w, const float* q_w, int l, int b, float* s_wA){
  if (threadIdx.x < 64) return;
  for (int i = (int)threadIdx.x - 64; i < 768; i += 192){
    int j = i >> 7, off = i & 127;
    int r = b*6 + j;
    float4 v;
    if (r < 2*DM) v = ((const float4*)(kv_w + ((size_t)l*2*DM + r)*DM))[off];
    else          v = ((const float4*)(q_w  + ((size_t)l*DM + (r-2*DM))*DM))[off];
    ((float4*)(s_wA + j*DM))[off] = v;
  }
}

__global__ __launch_bounds__(BLK, 1) void wf_kernel(
    const float* __restrict__ y,      const float* __restrict__ samples,
    const float* __restrict__ emb,    const float* __restrict__ condW,
    const float* __restrict__ ln_w,   const float* __restrict__ ln_b,
    const float* __restrict__ kv_w,   const float* __restrict__ kv_b,
    const float* __restrict__ q_w,    const float* __restrict__ q_b,
    const float* __restrict__ o_w,    const float* __restrict__ o_b,
    const float* __restrict__ fln_w,  const float* __restrict__ fln_b,
    const float* __restrict__ ff_w1,  const float* __restrict__ ff_b1,
    const float* __restrict__ ff_w2,  const float* __restrict__ ff_b2,
    const float* __restrict__ head_r, const float* __restrict__ last_w,
    const float* __restrict__ last_b,
    int* __restrict__ outp, float* __restrict__ ws,
    float* __restrict__ kvhist,   // non-null => write-once KV history mode
    float* __restrict__ w2T)      // non-null => pre-transposed ff_w2 slices
{
  const int tid  = threadIdx.x;
  const int b    = blockIdx.x;
  const int lane = tid & 63;
  const int wid  = tid >> 6;
  const int kz   = b >> 5;            // partial-accumulator index (fan-in 32)
  const int ez0  = (b & 31) * 16;     // 16 accumulator elements this block maintains

  u32*   flags  = (u32*)ws;                 // 1 KiB, zeroed by memset
  float* embt   = ws + 4096;                // 256*512
  float* ycond  = embt + NCLS*DM;           // 512*512
  float* kvc    = ycond + TT*DM;            // 8*32*1024 (ring; unused in hist mode)
  float* hq     = kvc + LAYERS*WIN*2*DM;    // 512
  float* xpart  = hq + DM;                  // [2][8][512] ping-pong x partials
  float* xc2p   = xpart + 2*8*DM;           // [8][512] xc2 partials
  float* logitb = xc2p + 8*DM;              // 256
  float* o_wT   = logitb + NCLS;            // 8*512*512 transposed o_w

  __shared__ __align__(16) float s_wA[6*DM];   // kv/q rows
  __shared__ __align__(16) float s_wB[8*DM];   // ff1 rows
  __shared__ __align__(16) float s_wC[8*DM];   // w2T slice [j][r]
  __shared__ __align__(16) float s_wO[2*DM];   // o_wT rows
  __shared__ __align__(16) float s_wL[DM];     // last_w row
  __shared__ __align__(16) float s_xc[DM];
  __shared__ __align__(16) float s_tmp[DM];
  __shared__ __align__(16) float s_q[DHD];
  __shared__ float s_part[BLK];
  __shared__ float s_red[8];
  __shared__ float s_red2[8];
  __shared__ float s_h8[8];
  __shared__ int   s_ired[4];
  __shared__ float s_y[MEL];

  int ph = 0;

  // ======== one-time precompute ========
  {
    const int gtid = b*BLK + tid;
    for (int i = gtid; i < NCLS*DM; i += GRID*BLK) st_sc(embt + i, tanhf(emb[i]));
  }
  for (int k = 0; k < 2; k++){
    int t0 = b*2 + k;
    if (tid < MEL) s_y[tid] = y[tid*TT + t0];
    __syncthreads();
    for (int dd = tid; dd < DM; dd += BLK){
      const float* cw = condW + dd*MEL;
      float acc = 0.f;
#pragma unroll
      for (int m4 = 0; m4 < MEL; m4 += 4){
        float4 c4 = *(const float4*)(cw + m4);
        acc += c4.x*s_y[m4] + c4.y*s_y[m4+1] + c4.z*s_y[m4+2] + c4.w*s_y[m4+3];
      }
      st_sc(ycond + t0*DM + dd, acc);
    }
    __syncthreads();
  }
  // o_wT[l][c][r] = o_w[l][r][c]
  {
    int l = b >> 5, r0 = (b & 31)*16;
    for (int rr = 0; rr < 16; rr++){
      int r = r0 + rr;
      const float* src = o_w + ((size_t)l*DM + r)*DM;
      float v0 = src[tid], v1 = src[tid+256];
      st_sc(o_wT + ((size_t)l*DM + tid)*DM + r, v0);
      st_sc(o_wT + ((size_t)l*DM + tid+256)*DM + r, v1);
    }
  }
  // w2T[l][b][j][r] = ff_w2[l][r][b*8+j] — block-private slices (plain st/ld:
  // only block b ever reads w2T[l][b], and it runs on one CU the whole kernel,
  // so same-L2 coherence suffices; no agent scope needed). Turns the per-step
  // B2 prefetch from 512x32B@8KB-stride into one contiguous 16KB copy.
  if (w2T){
    for (int l2 = 0; l2 < LAYERS; l2++){
      float* dst = w2T + ((size_t)(l2*GRID + b))*8*DM;
      for (int r = tid; r < DM; r += BLK){
        const float* src = ff_w2 + ((size_t)l2*DM + r)*DFF + b*8;
        float4 a = *(const float4*)(src);
        float4 c4 = *(const float4*)(src + 4);
        dst[0*DM+r]=a.x;  dst[1*DM+r]=a.y;  dst[2*DM+r]=a.z;  dst[3*DM+r]=a.w;
        dst[4*DM+r]=c4.x; dst[5*DM+r]=c4.y; dst[6*DM+r]=c4.z; dst[7*DM+r]=c4.w;
      }
    }
  }
  ph++;
  bar_arrive(flags, b, ph);
  pf_kvq192(kv_w, q_w, 0, b, s_wA);
  bar_wait(flags, ph);

  int cur_idx = NCLS/2 - 1;
  const float scale = 0.125f;
  const int hh = b >> 5, gg = b & 31;     // attention assignment

  for (int t = 0; t < TT; t++){
    float* cond = ycond + t*DM;
    const int slot = t & (WIN-1);
    const int wlo  = (t >= WIN-1) ? 0 : (WIN-1 - t);

    for (int l = 0; l < LAYERS; l++){
      float* xcur = xpart + (l&1)*8*DM;        // read partials (l>0)
      float* xnxt = xpart + ((l+1)&1)*8*DM;    // target partials for next x

      // ========== seg1: xc (gather), LN1, KV/Q matvec; zero/seed partials ==========
      {
        float2 xv;
        if (l == 0){
          xv = *(const float2*)(embt + cur_idx*DM + 2*tid);
        } else {
          xv = make_float2(0.f, 0.f);
#pragma unroll
          for (int k = 0; k < 8; k++){
            float2 p = ld_sc2(xcur + k*DM + 2*tid);
            xv.x += p.x; xv.y += p.y;
          }
        }
        float2 cv = *(const float2*)(cond + 2*tid);
        s_xc[2*tid]   = cv.x + xv.x;
        s_xc[2*tid+1] = cv.y + xv.y;
      }
      __syncthreads();
      layernorm512(s_xc, s_tmp, ln_w + l*DM, ln_b + l*DM, tid, lane, wid, s_red, s_red2);
      __syncthreads();
      {
        // zero next-x partial; zero-or-seed xc2 partial (16 els each, single writer)
        if (tid < 16){
          int e = ez0 + tid;
          st_sc(xnxt + kz*DM + e, 0.f);
          float seed = (kz == 0) ? s_xc[e] + o_b[l*DM + e] : 0.f;
          st_sc(xc2p + kz*DM + e, seed);
        }
        // hist mode: rows advance monotonically with t (write-once); ring otherwise
        float* cacheRow = kvhist ? (kvhist + (size_t)(l*TT + t)*KVROW)
                                 : (kvc + ((size_t)(l*WIN + slot) << 10));
        for (int j = wid; j < 6; j += 4){
          int r = b*6 + j;
          float dv = dot512(s_wA + j*DM, s_tmp, lane);
          if (r < 2*DM){
            dv += kv_b[l*2*DM + r];
            if (lane == 0) st_sc(cacheRow + r, dv);
          } else {
            int rq = r - 2*DM;
            dv += q_b[l*DM + rq];
            if (lane == 0) st_sc(hq + rq, dv);
          }
        }
      }
      ph++;
      bar_arrive(flags, b, ph);
      pf_copy192(ff_w1 + ((size_t)l*DFF + b*8)*DM, s_wB, 8*128);
      pf_copy192(o_wT + ((size_t)(l*DM + hh*DHD + gg*2))*DM, s_wO, 2*128);
      bar_wait(flags, ph);

      // ========== seg2: distributed attention + o_w partial (8-way partials) ==========
      {
        int w = tid >> 3, j = tid & 7;
        float2 k0, k1, k2, k3;
        float2 v2 = make_float2(0.f, 0.f);
        if (kvhist){
          // write-once rows: plain cached reads are coherent (first touch of any
          // row address is always after the producing barrier; 31/32 rows hit L1/L2)
          int tp = t - (WIN-1) + w; if (tp < 0) tp = 0;   // masked slots clamp to row 0
          const float* kk = kvhist + (size_t)(l*TT + tp)*KVROW + hh*DHD + j*8;
          k0 = *(const float2*)(kk);   k1 = *(const float2*)(kk+2);
          k2 = *(const float2*)(kk+4); k3 = *(const float2*)(kk+6);
          if (tid < 32){
            int tv = t - (WIN-1) + tid; if (tv < 0) tv = 0;
            v2 = *(const float2*)(kvhist + (size_t)(l*TT + tv)*KVROW + DM + hh*DHD + gg*2);
            float2 qv = ld_sc2(hq + hh*DHD + 2*tid);     // hq fresh each phase: stays coherent
            s_q[2*tid] = qv.x; s_q[2*tid+1] = qv.y;
          }
        } else {
          int c = (t + 1 + w) & (WIN-1);
          float* kk = kvc + ((size_t)(l*WIN + c) << 10) + hh*DHD + j*8;
          k0 = ld_sc2(kk); k1 = ld_sc2(kk+2); k2 = ld_sc2(kk+4); k3 = ld_sc2(kk+6);
          if (tid < 32){
            int cv2 = (t + 1 + tid) & (WIN-1);
            v2 = ld_sc2(kvc + ((size_t)(l*WIN + cv2) << 10) + DM + hh*DHD + gg*2);
            float2 qv = ld_sc2(hq + hh*DHD + 2*tid);
            s_q[2*tid] = qv.x; s_q[2*tid+1] = qv.y;
          }
        }
        __syncthreads();
        const float* rr = head_r + (((size_t)(l*WIN + w)*NH + hh) << 6) + j*8;
        float2 r0 = *(const float2*)(rr),   r1 = *(const float2*)(rr+2);
        float2 r2 = *(const float2*)(rr+4), r3 = *(const float2*)(rr+6);
        const float* qq = s_q + j*8;
        float acc = (k0.x+r0.x)*qq[0] + (k0.y+r0.y)*qq[1]
                  + (k1.x+r1.x)*qq[2] + (k1.y+r1.y)*qq[3]
                  + (k2.x+r2.x)*qq[4] + (k2.y+r2.y)*qq[5]
                  + (k3.x+r3.x)*qq[6] + (k3.y+r3.y)*qq[7];
        s_part[tid] = acc;
        __syncthreads();
        if (tid < 32){
          float sc = 0.f;
#pragma unroll
          for (int jj = 0; jj < 8; jj++) sc += s_part[tid*8 + jj];
          sc *= scale;
          float sval = (tid >= wlo) ? sc : -INFINITY;
          float m = sval;
#pragma unroll
          for (int mm = 16; mm >= 1; mm >>= 1) m = fmaxf(m, __shfl_xor(m, mm, 64));
          float p = (tid >= wlo) ? expf(sval - m) : 0.f;
          float den = p;
#pragma unroll
          for (int mm = 16; mm >= 1; mm >>= 1) den += __shfl_xor(den, mm, 64);
          float at = p / den;
          float ox = at*v2.x, oy = at*v2.y;
#pragma unroll
          for (int mm = 16; mm >= 1; mm >>= 1){
            ox += __shfl_xor(ox, mm, 64); oy += __shfl_xor(oy, mm, 64);
          }
          if (tid == 0){ s_red[0] = ox; s_red[1] = oy; }
        }
        __syncthreads();
        float o0 = s_red[0], o1 = s_red[1];
        float p0 = s_wO[tid]*o0     + s_wO[DM + tid]*o1;
        float p1 = s_wO[tid+256]*o0 + s_wO[DM + tid+256]*o1;
        unsafeAtomicAdd(xc2p + kz*DM + tid,       p0);
        unsafeAtomicAdd(xc2p + kz*DM + tid + 256, p1);
      }
      ph++;
      bar_arrive(flags, b, ph);
      if (w2T){
        pf_copy192(w2T + ((size_t)(l*GRID + b))*8*DM, s_wC, 8*128);
      } else {
        // fallback: strided gather s_wC[j][r] = ff_w2[l][r][b*8+j] (waves 1-3)
        if (tid >= 64){
          for (int rr2 = tid - 64; rr2 < DM; rr2 += 192){
            const float* src = ff_w2 + ((size_t)l*DM + rr2)*DFF + b*8;
            float4 a = *(const float4*)(src);
            float4 c4 = *(const float4*)(src + 4);
            s_wC[0*DM+rr2]=a.x;  s_wC[1*DM+rr2]=a.y;  s_wC[2*DM+rr2]=a.z;  s_wC[3*DM+rr2]=a.w;
            s_wC[4*DM+rr2]=c4.x; s_wC[5*DM+rr2]=c4.y; s_wC[6*DM+rr2]=c4.z; s_wC[7*DM+rr2]=c4.w;
          }
        }
      }
      bar_wait(flags, ph);

      // ========== seg3: gather xc2, LN2 + FFN1 + FFN2-partial (fused) ==========
      {
        float2 x2 = make_float2(0.f, 0.f);
#pragma unroll
        for (int k = 0; k < 8; k++){
          float2 p = ld_sc2(xc2p + k*DM + 2*tid);
          x2.x += p.x; x2.y += p.y;
        }
        s_xc[2*tid] = x2.x; s_xc[2*tid+1] = x2.y;
      }
      __syncthreads();
      layernorm512(s_xc, s_tmp, fln_w + l*DM, fln_b + l*DM, tid, lane, wid, s_red, s_red2);
      __syncthreads();
      {
        for (int j2 = 0; j2 < 2; j2++){
          int j = wid*2 + j2;
          float dv = dot512(s_wB + j*DM, s_tmp, lane) + ff_b1[l*DFF + b*8 + j];
          if (lane == 0) s_h8[j] = gelu_tanh(dv);
        }
      }
      __syncthreads();
      {
        float h0=s_h8[0], h1=s_h8[1], h2=s_h8[2], h3=s_h8[3];
        float h4=s_h8[4], h5=s_h8[5], h6=s_h8[6], h7=s_h8[7];
        int r0 = tid, r1 = tid + 256;
        float p0 = s_wC[r0]*h0 + s_wC[DM+r0]*h1 + s_wC[2*DM+r0]*h2 + s_wC[3*DM+r0]*h3
                 + s_wC[4*DM+r0]*h4 + s_wC[5*DM+r0]*h5 + s_wC[6*DM+r0]*h6 + s_wC[7*DM+r0]*h7;
        float p1 = s_wC[r1]*h0 + s_wC[DM+r1]*h1 + s_wC[2*DM+r1]*h2 + s_wC[3*DM+r1]*h3
                 + s_wC[4*DM+r1]*h4 + s_wC[5*DM+r1]*h5 + s_wC[6*DM+r1]*h6 + s_wC[7*DM+r1]*h7;
        if (r0 == b*2)     p0 += s_xc[r0] + ff_b2[l*DM + r0];
        if (r0 == b*2 + 1) p0 += s_xc[r0] + ff_b2[l*DM + r0];
        if (r1 == b*2)     p1 += s_xc[r1] + ff_b2[l*DM + r1];
        if (r1 == b*2 + 1) p1 += s_xc[r1] + ff_b2[l*DM + r1];
        unsafeAtomicAdd(xnxt + kz*DM + r0, p0);
        unsafeAtomicAdd(xnxt + kz*DM + r1, p1);
      }
      ph++;
      bar_arrive(flags, b, ph);
      if (l < LAYERS-1) pf_kvq192(kv_w, q_w, l+1, b, s_wA);
      else              pf_copy192(last_w + (size_t)b*DM, s_wL, 128);
      bar_wait(flags, ph);
    } // layers

    // ========== head: gather x8 + logits (1 row per block) ==========
    {
      float2 xv = make_float2(0.f, 0.f);
#pragma unroll
      for (int k = 0; k < 8; k++){
        float2 p = ld_sc2(xpart + k*DM + 2*tid);    // x8 in xpart[0]
        xv.x += p.x; xv.y += p.y;
      }
      s_tmp[2*tid] = xv.x; s_tmp[2*tid+1] = xv.y;
    }
    __syncthreads();
    if (wid == 0){
      float dv = dot512(s_wL, s_tmp, lane) + last_b[b];
      if (lane == 0) st_sc(logitb + b, dv);
    }
    ph++;
    bar_arrive(flags, b, ph);
    pf_kvq192(kv_w, q_w, 0, b, s_wA);     // layer-0 weights for next step
    bar_wait(flags, ph);

    // ===== sampling (redundant per block; deterministic within run; no barrier) =====
    {
      float u  = samples[t];
      float li = ld_sc(logitb + tid);
      float mx = wredmax(li);
      if (lane == 0) s_red[wid] = mx;
      __syncthreads();
      mx = fmaxf(fmaxf(s_red[0], s_red[1]), fmaxf(s_red[2], s_red[3]));
      float p  = expf(li - mx);
      float sm = wredsum(p);
      __syncthreads();
      if (lane == 0) s_red[wid] = sm;
      __syncthreads();
      float den = s_red[0]+s_red[1]+s_red[2]+s_red[3];
      float q = p / den;
      float x = q;
#pragma unroll
      for (int off = 1; off < 64; off <<= 1){
        float n = __shfl_up(x, off, 64);
        if (lane >= off) x += n;
      }
      __syncthreads();
      if (lane == 63) s_red[wid] = x;
      __syncthreads();
      float offs = 0.f;
      for (int j2 = 0; j2 < wid; j2++) offs += s_red[j2];
      float cum = x + offs;
      unsigned long long bal = __ballot(cum > u);
      int first = (bal != 0ULL) ? (__ffsll(bal) - 1) : 9999;
      if (lane == 0) s_ired[wid] = (first < 9999) ? (wid*64 + first) : 9999;
      __syncthreads();
      int idx = min(min(s_ired[0], s_ired[1]), min(s_ired[2], s_ired[3]));
      if (idx == 9999) idx = 0;
      cur_idx = idx;
      if (b == 0 && tid == 0) outp[t] = idx;
      __syncthreads();
    }
  } // t
}

extern "C" void kernel_launch(void* const* d_in, const int* in_sizes, int n_in,
                              void* d_out, int out_size, void* d_ws, size_t ws_size,
                              hipStream_t stream)
{
  (void)in_sizes; (void)n_in; (void)out_size;
  hipMemsetAsync(d_ws, 0, 2048, stream);   // zero barrier flags (1 KiB used)

  const float* y      = (const float*)d_in[0];
  const float* samp   = (const float*)d_in[1];
  const float* emb    = (const float*)d_in[2];
  const float* condW  = (const float*)d_in[3];
  const float* ln_w   = (const float*)d_in[4];
  const float* ln_b   = (const float*)d_in[5];
  const float* kv_w   = (const float*)d_in[6];
  const float* kv_b   = (const float*)d_in[7];
  const float* q_w    = (const float*)d_in[8];
  const float* q_b    = (const float*)d_in[9];
  const float* o_w    = (const float*)d_in[10];
  const float* o_b    = (const float*)d_in[11];
  const float* fln_w  = (const float*)d_in[12];
  const float* fln_b  = (const float*)d_in[13];
  const float* ff_w1  = (const float*)d_in[14];
  const float* ff_b1  = (const float*)d_in[15];
  const float* ff_w2  = (const float*)d_in[16];
  const float* ff_b2  = (const float*)d_in[17];
  const float* head_r = (const float*)d_in[18];
  const float* last_w = (const float*)d_in[19];
  const float* last_b = (const float*)d_in[20];

  // workspace layout (floats): flags/embt/ycond/kvc/hq/xpart/xc2p/logitb/o_wT | kvhist | w2T
  const size_t baseFloats = 4096 + (size_t)NCLS*DM + (size_t)TT*DM
                          + (size_t)LAYERS*WIN*2*DM + DM + 2*8*DM + 8*DM + NCLS
                          + (size_t)LAYERS*DM*DM;                 // = 2,769,664
  const size_t histFloats = (size_t)LAYERS*TT*KVROW;              // = 4,325,376
  const size_t w2tFloats  = (size_t)LAYERS*GRID*8*DM;             // = 8,388,608
  const size_t needHist   = (baseFloats + histFloats) * sizeof(float);
  const size_t needW2T    = (baseFloats + histFloats + w2tFloats) * sizeof(float);
  float* kvhist = (ws_size >= needHist) ? ((float*)d_ws + baseFloats) : nullptr;
  float* w2T    = (ws_size >= needW2T)  ? ((float*)d_ws + baseFloats + histFloats) : nullptr;

  wf_kernel<<<GRID, BLK, 0, stream>>>(y, samp, emb, condW, ln_w, ln_b, kv_w, kv_b,
                                      q_w, q_b, o_w, o_b, fln_w, fln_b,
                                      ff_w1, ff_b1, ff_w2, ff_b2, head_r,
                                      last_w, last_b,
                                      (int*)d_out, (float*)d_ws, kvhist, w2T);
}

// Round 11
// 50734.866 us; speedup vs baseline: 1.6866x; 1.6866x over previous
//
#include <hip/hip_runtime.h>
#include <math.h>

// ---- model dims ----
#define LAYERS 8
#define WIN    32
#define NH     8
#define DHD    64
#define DM     512
#define DFF    2048
#define NCLS   256
#define MEL    80
#define TT     512

// ---- persistent kernel: 256 blocks x 256 threads (1 block/CU) ----
#define GRID   256
#define BLK    256

// KV history row: 1024 data floats + 32 pad floats (one 128B line) so a
// depth-1 next-line prefetch can never pull an unwritten future row.
#define KVROW  1056

typedef unsigned int  u32;
typedef unsigned long long u64;

// ---- wave=64 reductions ----
__device__ inline float wredsum(float v){
#pragma unroll
  for (int m = 32; m >= 1; m >>= 1) v += __shfl_xor(v, m, 64);
  return v;
}
__device__ inline float wredmax(float v){
#pragma unroll
  for (int m = 32; m >= 1; m >>= 1) v = fmaxf(v, __shfl_xor(v, m, 64));
  return v;
}

// ---- coherent (sc-bit) comm ops: relaxed agent scope ----
__device__ inline float ld_sc(float* p){
  return __hip_atomic_load(p, __ATOMIC_RELAXED, __HIP_MEMORY_SCOPE_AGENT);
}
__device__ inline void st_sc(float* p, float v){
  __hip_atomic_store(p, v, __ATOMIC_RELAXED, __HIP_MEMORY_SCOPE_AGENT);
}
__device__ inline float2 ld_sc2(float* p){
  u64 u = __hip_atomic_load((u64*)p, __ATOMIC_RELAXED, __HIP_MEMORY_SCOPE_AGENT);
  union { u64 u; float2 f; } cv; cv.u = u; return cv.f;
}

// dot(row512_in_LDS, vec512_in_LDS) across one wave
__device__ inline float dot512(const float* w, const float* vec, int lane){
  float4 a0 = *(const float4*)(w + 4*lane);
  float4 a1 = *(const float4*)(w + 256 + 4*lane);
  float4 b0 = *(const float4*)(vec + 4*lane);
  float4 b1 = *(const float4*)(vec + 256 + 4*lane);
  float p = a0.x*b0.x + a0.y*b0.y + a0.z*b0.z + a0.w*b0.w
          + a1.x*b1.x + a1.y*b1.y + a1.z*b1.z + a1.w*b1.w;
  return wredsum(p);
}

__device__ inline float gelu_tanh(float x){
  float x3 = x*x*x;
  return 0.5f*x*(1.0f + tanhf(0.7978845608028654f*(x + 0.044715f*x3)));
}

// ---- split-phase barrier: u32 flags spread over 8 cache lines ----
// MEASURED post-mortem (R5): the wave-role-split variant (wave0 polls,
// waves1-3 prefetch with stride-192 variable-trip loops) regressed 55->82ms.
// Cause: non-exact trip counts + no unroll serialized the prefetch into
// 5-6 dependent load->wait->store latencies. The 256-thread exact-division
// #pragma-unroll prefetch (below) batches loads and costs ~1 latency.
__device__ inline void bar_arrive(u32* flags, int b, int ph){
  __syncthreads();   // drains vmcnt: all sc stores/atomics of this block visible
  if (threadIdx.x == 0)
    __hip_atomic_store(flags + b, (u32)ph, __ATOMIC_RELAXED, __HIP_MEMORY_SCOPE_AGENT);
}
__device__ inline void bar_wait(u32* flags, int ph){
  int tid = threadIdx.x;
  if (tid < 64){
    u64* fp = (u64*)flags + 2*tid;    // lane i watches flags[4i..4i+4)
    for (;;){
      u64 v0 = __hip_atomic_load(fp,     __ATOMIC_RELAXED, __HIP_MEMORY_SCOPE_AGENT);
      u64 v1 = __hip_atomic_load(fp + 1, __ATOMIC_RELAXED, __HIP_MEMORY_SCOPE_AGENT);
      u32 a0 = (u32)v0, a1 = (u32)(v0 >> 32);
      u32 a2 = (u32)v1, a3 = (u32)(v1 >> 32);
      if (min(min(a0, a1), min(a2, a3)) >= (u32)ph) break;
      __builtin_amdgcn_s_sleep(2);
    }
  }
  asm volatile("" ::: "memory");
  __syncthreads();
}

// fused single-pass LN over 512 els in LDS (src -> dst), stats via sum+sumsq
// in ONE interleaved reduction round. Caller must __syncthreads() after.
__device__ inline void layernorm512(const float* __restrict__ src,
                                    float* __restrict__ dst,
                                    const float* __restrict__ w,
                                    const float* __restrict__ bb,
                                    int tid, int lane, int wid,
                                    float* s_red, float* s_red2){
  float a = src[tid], c = src[tid + 256];
  float p1 = a + c;
  float p2 = a*a + c*c;
#pragma unroll
  for (int m = 32; m >= 1; m >>= 1){
    p1 += __shfl_xor(p1, m, 64);
    p2 += __shfl_xor(p2, m, 64);
  }
  if (lane == 0){ s_red[wid] = p1; s_red2[wid] = p2; }
  __syncthreads();
  float mu  = (s_red[0]+s_red[1]+s_red[2]+s_red[3])   * (1.0f/512.0f);
  float ex2 = (s_red2[0]+s_red2[1]+s_red2[2]+s_red2[3]) * (1.0f/512.0f);
  float var = fmaxf(ex2 - mu*mu, 0.0f);           // guard tiny negative
  float rsig = 1.0f / sqrtf(var + 1e-5f);
  dst[tid]       = (a - mu)*rsig*w[tid]       + bb[tid];
  dst[tid + 256] = (c - mu)*rsig*w[tid + 256] + bb[tid + 256];
}

// float4 global->LDS copy (all 256 threads, exact division, batched loads)
__device__ inline void pf_copy(const float* __restrict__ g, float* l, int n4){
  const float4* g4 = (const float4*)g;
  float4* l4 = (float4*)l;
#pragma unroll 4
  for (int i = threadIdx.x; i < n4; i += BLK) l4[i] = g4[i];
}

// prefetch this block's 6 kv/q rows for layer l into s_wA (3072 floats)
__device__ inline void pf_kvq(const float* kv_w, const float* q_w, int l, int b, float* s_wA){
  for (int i = threadIdx.x; i < 768; i += BLK){
    int j = i >> 7, off = i & 127;
    int r = b*6 + j;
    float4 v;
    if (r < 2*DM) v = ((const float4*)(kv_w + ((size_t)l*2*DM + r)*DM))[off];
    else          v = ((const float4*)(q_w  + ((size_t)l*DM + (r-2*DM))*DM))[off];
    ((float4*)(s_wA + j*DM))[off] = v;
  }
}

__global__ __launch_bounds__(BLK, 1) void wf_kernel(
    const float* __restrict__ y,      const float* __restrict__ samples,
    const float* __restrict__ emb,    const float* __restrict__ condW,
    const float* __restrict__ ln_w,   const float* __restrict__ ln_b,
    const float* __restrict__ kv_w,   const float* __restrict__ kv_b,
    const float* __restrict__ q_w,    const float* __restrict__ q_b,
    const float* __restrict__ o_w,    const float* __restrict__ o_b,
    const float* __restrict__ fln_w,  const float* __restrict__ fln_b,
    const float* __restrict__ ff_w1,  const float* __restrict__ ff_b1,
    const float* __restrict__ ff_w2,  const float* __restrict__ ff_b2,
    const float* __restrict__ head_r, const float* __restrict__ last_w,
    const float* __restrict__ last_b,
    int* __restrict__ outp, float* __restrict__ ws,
    float* __restrict__ kvhist,   // non-null => write-once KV history mode
    float* __restrict__ w2T)      // non-null => pre-transposed ff_w2 slices
{
  const int tid  = threadIdx.x;
  const int b    = blockIdx.x;
  const int lane = tid & 63;
  const int wid  = tid >> 6;
  const int kz   = b >> 5;            // partial-accumulator index (fan-in 32)
  const int ez0  = (b & 31) * 16;     // 16 accumulator elements this block maintains

  u32*   flags  = (u32*)ws;                 // 1 KiB, zeroed by memset
  float* embt   = ws + 4096;                // 256*512
  float* ycond  = embt + NCLS*DM;           // 512*512
  float* kvc    = ycond + TT*DM;            // 8*32*1024 (ring; unused in hist mode)
  float* hq     = kvc + LAYERS*WIN*2*DM;    // 512
  float* xpart  = hq + DM;                  // [2][8][512] ping-pong x partials
  float* xc2p   = xpart + 2*8*DM;           // [8][512] xc2 partials
  float* logitb = xc2p + 8*DM;              // 256
  float* o_wT   = logitb + NCLS;            // 8*512*512 transposed o_w

  __shared__ __align__(16) float s_wA[6*DM];   // kv/q rows
  __shared__ __align__(16) float s_wB[8*DM];   // ff1 rows
  __shared__ __align__(16) float s_wC[8*DM];   // w2T slice [j][r]
  __shared__ __align__(16) float s_wO[2*DM];   // o_wT rows
  __shared__ __align__(16) float s_wL[DM];     // last_w row
  __shared__ __align__(16) float s_xc[DM];
  __shared__ __align__(16) float s_tmp[DM];
  __shared__ __align__(16) float s_q[DHD];
  __shared__ float s_part[BLK];
  __shared__ float s_red[8];
  __shared__ float s_red2[8];
  __shared__ float s_h8[8];
  __shared__ int   s_ired[4];
  __shared__ float s_y[MEL];

  int ph = 0;

  // ======== one-time precompute ========
  {
    const int gtid = b*BLK + tid;
    for (int i = gtid; i < NCLS*DM; i += GRID*BLK) st_sc(embt + i, tanhf(emb[i]));
  }
  for (int k = 0; k < 2; k++){
    int t0 = b*2 + k;
    if (tid < MEL) s_y[tid] = y[tid*TT + t0];
    __syncthreads();
    for (int dd = tid; dd < DM; dd += BLK){
      const float* cw = condW + dd*MEL;
      float acc = 0.f;
#pragma unroll
      for (int m4 = 0; m4 < MEL; m4 += 4){
        float4 c4 = *(const float4*)(cw + m4);
        acc += c4.x*s_y[m4] + c4.y*s_y[m4+1] + c4.z*s_y[m4+2] + c4.w*s_y[m4+3];
      }
      st_sc(ycond + t0*DM + dd, acc);
    }
    __syncthreads();
  }
  // o_wT[l][c][r] = o_w[l][r][c]
  {
    int l = b >> 5, r0 = (b & 31)*16;
    for (int rr = 0; rr < 16; rr++){
      int r = r0 + rr;
      const float* src = o_w + ((size_t)l*DM + r)*DM;
      float v0 = src[tid], v1 = src[tid+256];
      st_sc(o_wT + ((size_t)l*DM + tid)*DM + r, v0);
      st_sc(o_wT + ((size_t)l*DM + tid+256)*DM + r, v1);
    }
  }
  // w2T[l][b][j][r] = ff_w2[l][r][b*8+j] — block-private slices (plain st/ld:
  // only block b ever reads w2T[l][b], and it stays on one CU the whole kernel,
  // so program order + same-L2 visibility suffices). Turns the per-step B2
  // prefetch from 512x32B@8KB-stride into one contiguous 16KB unrolled copy.
  // MEASURED (R5): halves FETCH_SIZE/step 106->58 MB.
  if (w2T){
    for (int l2 = 0; l2 < LAYERS; l2++){
      float* dst = w2T + ((size_t)(l2*GRID + b))*8*DM;
      for (int r = tid; r < DM; r += BLK){
        const float* src = ff_w2 + ((size_t)l2*DM + r)*DFF + b*8;
        float4 a = *(const float4*)(src);
        float4 c4 = *(const float4*)(src + 4);
        dst[0*DM+r]=a.x;  dst[1*DM+r]=a.y;  dst[2*DM+r]=a.z;  dst[3*DM+r]=a.w;
        dst[4*DM+r]=c4.x; dst[5*DM+r]=c4.y; dst[6*DM+r]=c4.z; dst[7*DM+r]=c4.w;
      }
    }
  }
  ph++;
  bar_arrive(flags, b, ph);
  pf_kvq(kv_w, q_w, 0, b, s_wA);
  bar_wait(flags, ph);

  int cur_idx = NCLS/2 - 1;
  const float scale = 0.125f;
  const int hh = b >> 5, gg = b & 31;     // attention assignment

  for (int t = 0; t < TT; t++){
    float* cond = ycond + t*DM;
    const int slot = t & (WIN-1);
    const int wlo  = (t >= WIN-1) ? 0 : (WIN-1 - t);

    for (int l = 0; l < LAYERS; l++){
      float* xcur = xpart + (l&1)*8*DM;        // read partials (l>0)
      float* xnxt = xpart + ((l+1)&1)*8*DM;    // target partials for next x

      // ========== seg1: xc (gather), LN1, KV/Q matvec; zero/seed partials ==========
      {
        float2 xv;
        if (l == 0){
          xv = *(const float2*)(embt + cur_idx*DM + 2*tid);
        } else {
          xv = make_float2(0.f, 0.f);
#pragma unroll
          for (int k = 0; k < 8; k++){
            float2 p = ld_sc2(xcur + k*DM + 2*tid);
            xv.x += p.x; xv.y += p.y;
          }
        }
        float2 cv = *(const float2*)(cond + 2*tid);
        s_xc[2*tid]   = cv.x + xv.x;
        s_xc[2*tid+1] = cv.y + xv.y;
      }
      __syncthreads();
      layernorm512(s_xc, s_tmp, ln_w + l*DM, ln_b + l*DM, tid, lane, wid, s_red, s_red2);
      __syncthreads();
      {
        // zero next-x partial; zero-or-seed xc2 partial (16 els each, single writer)
        if (tid < 16){
          int e = ez0 + tid;
          st_sc(xnxt + kz*DM + e, 0.f);
          float seed = (kz == 0) ? s_xc[e] + o_b[l*DM + e] : 0.f;
          st_sc(xc2p + kz*DM + e, seed);
        }
        // hist mode: rows advance monotonically with t (write-once); ring otherwise
        float* cacheRow = kvhist ? (kvhist + (size_t)(l*TT + t)*KVROW)
                                 : (kvc + ((size_t)(l*WIN + slot) << 10));
        for (int j = wid; j < 6; j += 4){
          int r = b*6 + j;
          float dv = dot512(s_wA + j*DM, s_tmp, lane);
          if (r < 2*DM){
            dv += kv_b[l*2*DM + r];
            if (lane == 0) st_sc(cacheRow + r, dv);
          } else {
            int rq = r - 2*DM;
            dv += q_b[l*DM + rq];
            if (lane == 0) st_sc(hq + rq, dv);
          }
        }
      }
      ph++;
      bar_arrive(flags, b, ph);
      pf_copy(ff_w1 + ((size_t)l*DFF + b*8)*DM, s_wB, 8*128);
      pf_copy(o_wT + ((size_t)(l*DM + hh*DHD + gg*2))*DM, s_wO, 2*128);
      bar_wait(flags, ph);

      // ========== seg2: distributed attention + o_w partial (8-way partials) ==========
      {
        int w = tid >> 3, j = tid & 7;
        float2 k0, k1, k2, k3;
        float2 v2 = make_float2(0.f, 0.f);
        if (kvhist){
          // write-once rows: plain cached reads are coherent (first touch of any
          // row address is always after the producing barrier; 31/32 rows hit L1/L2)
          int tp = t - (WIN-1) + w; if (tp < 0) tp = 0;   // masked slots clamp to row 0
          const float* kk = kvhist + (size_t)(l*TT + tp)*KVROW + hh*DHD + j*8;
          k0 = *(const float2*)(kk);   k1 = *(const float2*)(kk+2);
          k2 = *(const float2*)(kk+4); k3 = *(const float2*)(kk+6);
          if (tid < 32){
            int tv = t - (WIN-1) + tid; if (tv < 0) tv = 0;
            v2 = *(const float2*)(kvhist + (size_t)(l*TT + tv)*KVROW + DM + hh*DHD + gg*2);
            float2 qv = ld_sc2(hq + hh*DHD + 2*tid);     // hq fresh each phase: stays coherent
            s_q[2*tid] = qv.x; s_q[2*tid+1] = qv.y;
          }
        } else {
          int c = (t + 1 + w) & (WIN-1);
          float* kk = kvc + ((size_t)(l*WIN + c) << 10) + hh*DHD + j*8;
          k0 = ld_sc2(kk); k1 = ld_sc2(kk+2); k2 = ld_sc2(kk+4); k3 = ld_sc2(kk+6);
          if (tid < 32){
            int cv2 = (t + 1 + tid) & (WIN-1);
            v2 = ld_sc2(kvc + ((size_t)(l*WIN + cv2) << 10) + DM + hh*DHD + gg*2);
            float2 qv = ld_sc2(hq + hh*DHD + 2*tid);
            s_q[2*tid] = qv.x; s_q[2*tid+1] = qv.y;
          }
        }
        __syncthreads();
        const float* rr = head_r + (((size_t)(l*WIN + w)*NH + hh) << 6) + j*8;
        float2 r0 = *(const float2*)(rr),   r1 = *(const float2*)(rr+2);
        float2 r2 = *(const float2*)(rr+4), r3 = *(const float2*)(rr+6);
        const float* qq = s_q + j*8;
        float acc = (k0.x+r0.x)*qq[0] + (k0.y+r0.y)*qq[1]
                  + (k1.x+r1.x)*qq[2] + (k1.y+r1.y)*qq[3]
                  + (k2.x+r2.x)*qq[4] + (k2.y+r2.y)*qq[5]
                  + (k3.x+r3.x)*qq[6] + (k3.y+r3.y)*qq[7];
        s_part[tid] = acc;
        __syncthreads();
        if (tid < 32){
          float sc = 0.f;
#pragma unroll
          for (int jj = 0; jj < 8; jj++) sc += s_part[tid*8 + jj];
          sc *= scale;
          float sval = (tid >= wlo) ? sc : -INFINITY;
          float m = sval;
#pragma unroll
          for (int mm = 16; mm >= 1; mm >>= 1) m = fmaxf(m, __shfl_xor(m, mm, 64));
          float p = (tid >= wlo) ? expf(sval - m) : 0.f;
          float den = p;
#pragma unroll
          for (int mm = 16; mm >= 1; mm >>= 1) den += __shfl_xor(den, mm, 64);
          float at = p / den;
          float ox = at*v2.x, oy = at*v2.y;
#pragma unroll
          for (int mm = 16; mm >= 1; mm >>= 1){
            ox += __shfl_xor(ox, mm, 64); oy += __shfl_xor(oy, mm, 64);
          }
          if (tid == 0){ s_red[0] = ox; s_red[1] = oy; }
        }
        __syncthreads();
        float o0 = s_red[0], o1 = s_red[1];
        float p0 = s_wO[tid]*o0     + s_wO[DM + tid]*o1;
        float p1 = s_wO[tid+256]*o0 + s_wO[DM + tid+256]*o1;
        unsafeAtomicAdd(xc2p + kz*DM + tid,       p0);
        unsafeAtomicAdd(xc2p + kz*DM + tid + 256, p1);
      }
      ph++;
      bar_arrive(flags, b, ph);
      if (w2T){
        pf_copy(w2T + ((size_t)(l*GRID + b))*8*DM, s_wC, 8*128);
      } else {
        // fallback: strided gather s_wC[j][r] = ff_w2[l][r][b*8+j]
        for (int rr2 = tid; rr2 < DM; rr2 += BLK){
          const float* src = ff_w2 + ((size_t)l*DM + rr2)*DFF + b*8;
          float4 a = *(const float4*)(src);
          float4 c4 = *(const float4*)(src + 4);
          s_wC[0*DM+rr2]=a.x;  s_wC[1*DM+rr2]=a.y;  s_wC[2*DM+rr2]=a.z;  s_wC[3*DM+rr2]=a.w;
          s_wC[4*DM+rr2]=c4.x; s_wC[5*DM+rr2]=c4.y; s_wC[6*DM+rr2]=c4.z; s_wC[7*DM+rr2]=c4.w;
        }
      }
      bar_wait(flags, ph);

      // ========== seg3: gather xc2, LN2 + FFN1 + FFN2-partial (fused) ==========
      {
        float2 x2 = make_float2(0.f, 0.f);
#pragma unroll
        for (int k = 0; k < 8; k++){
          float2 p = ld_sc2(xc2p + k*DM + 2*tid);
          x2.x += p.x; x2.y += p.y;
        }
        s_xc[2*tid] = x2.x; s_xc[2*tid+1] = x2.y;
      }
      __syncthreads();
      layernorm512(s_xc, s_tmp, fln_w + l*DM, fln_b + l*DM, tid, lane, wid, s_red, s_red2);
      __syncthreads();
      {
        for (int j2 = 0; j2 < 2; j2++){
          int j = wid*2 + j2;
          float dv = dot512(s_wB + j*DM, s_tmp, lane) + ff_b1[l*DFF + b*8 + j];
          if (lane == 0) s_h8[j] = gelu_tanh(dv);
        }
      }
      __syncthreads();
      {
        float h0=s_h8[0], h1=s_h8[1], h2=s_h8[2], h3=s_h8[3];
        float h4=s_h8[4], h5=s_h8[5], h6=s_h8[6], h7=s_h8[7];
        int r0 = tid, r1 = tid + 256;
        float p0 = s_wC[r0]*h0 + s_wC[DM+r0]*h1 + s_wC[2*DM+r0]*h2 + s_wC[3*DM+r0]*h3
                 + s_wC[4*DM+r0]*h4 + s_wC[5*DM+r0]*h5 + s_wC[6*DM+r0]*h6 + s_wC[7*DM+r0]*h7;
        float p1 = s_wC[r1]*h0 + s_wC[DM+r1]*h1 + s_wC[2*DM+r1]*h2 + s_wC[3*DM+r1]*h3
                 + s_wC[4*DM+r1]*h4 + s_wC[5*DM+r1]*h5 + s_wC[6*DM+r1]*h6 + s_wC[7*DM+r1]*h7;
        if (r0 == b*2)     p0 += s_xc[r0] + ff_b2[l*DM + r0];
        if (r0 == b*2 + 1) p0 += s_xc[r0] + ff_b2[l*DM + r0];
        if (r1 == b*2)     p1 += s_xc[r1] + ff_b2[l*DM + r1];
        if (r1 == b*2 + 1) p1 += s_xc[r1] + ff_b2[l*DM + r1];
        unsafeAtomicAdd(xnxt + kz*DM + r0, p0);
        unsafeAtomicAdd(xnxt + kz*DM + r1, p1);
      }
      ph++;
      bar_arrive(flags, b, ph);
      if (l < LAYERS-1) pf_kvq(kv_w, q_w, l+1, b, s_wA);
      else              pf_copy(last_w + (size_t)b*DM, s_wL, 128);
      bar_wait(flags, ph);
    } // layers

    // ========== head: gather x8 + logits (1 row per block) ==========
    {
      float2 xv = make_float2(0.f, 0.f);
#pragma unroll
      for (int k = 0; k < 8; k++){
        float2 p = ld_sc2(xpart + k*DM + 2*tid);    // x8 in xpart[0]
        xv.x += p.x; xv.y += p.y;
      }
      s_tmp[2*tid] = xv.x; s_tmp[2*tid+1] = xv.y;
    }
    __syncthreads();
    if (wid == 0){
      float dv = dot512(s_wL, s_tmp, lane) + last_b[b];
      if (lane == 0) st_sc(logitb + b, dv);
    }
    ph++;
    bar_arrive(flags, b, ph);
    pf_kvq(kv_w, q_w, 0, b, s_wA);        // layer-0 weights for next step
    bar_wait(flags, ph);

    // ===== sampling (redundant per block; deterministic within run; no barrier) =====
    {
      float u  = samples[t];
      float li = ld_sc(logitb + tid);
      float mx = wredmax(li);
      if (lane == 0) s_red[wid] = mx;
      __syncthreads();
      mx = fmaxf(fmaxf(s_red[0], s_red[1]), fmaxf(s_red[2], s_red[3]));
      float p  = expf(li - mx);
      float sm = wredsum(p);
      __syncthreads();
      if (lane == 0) s_red[wid] = sm;
      __syncthreads();
      float den = s_red[0]+s_red[1]+s_red[2]+s_red[3];
      float q = p / den;
      float x = q;
#pragma unroll
      for (int off = 1; off < 64; off <<= 1){
        float n = __shfl_up(x, off, 64);
        if (lane >= off) x += n;
      }
      __syncthreads();
      if (lane == 63) s_red[wid] = x;
      __syncthreads();
      float offs = 0.f;
      for (int j2 = 0; j2 < wid; j2++) offs += s_red[j2];
      float cum = x + offs;
      unsigned long long bal = __ballot(cum > u);
      int first = (bal != 0ULL) ? (__ffsll(bal) - 1) : 9999;
      if (lane == 0) s_ired[wid] = (first < 9999) ? (wid*64 + first) : 9999;
      __syncthreads();
      int idx = min(min(s_ired[0], s_ired[1]), min(s_ired[2], s_ired[3]));
      if (idx == 9999) idx = 0;
      cur_idx = idx;
      if (b == 0 && tid == 0) outp[t] = idx;
      __syncthreads();
    }
  } // t
}

extern "C" void kernel_launch(void* const* d_in, const int* in_sizes, int n_in,
                              void* d_out, int out_size, void* d_ws, size_t ws_size,
                              hipStream_t stream)
{
  (void)in_sizes; (void)n_in; (void)out_size;
  hipMemsetAsync(d_ws, 0, 2048, stream);   // zero barrier flags (1 KiB used)

  const float* y      = (const float*)d_in[0];
  const float* samp   = (const float*)d_in[1];
  const float* emb    = (const float*)d_in[2];
  const float* condW  = (const float*)d_in[3];
  const float* ln_w   = (const float*)d_in[4];
  const float* ln_b   = (const float*)d_in[5];
  const float* kv_w   = (const float*)d_in[6];
  const float* kv_b   = (const float*)d_in[7];
  const float* q_w    = (const float*)d_in[8];
  const float* q_b    = (const float*)d_in[9];
  const float* o_w    = (const float*)d_in[10];
  const float* o_b    = (const float*)d_in[11];
  const float* fln_w  = (const float*)d_in[12];
  const float* fln_b  = (const float*)d_in[13];
  const float* ff_w1  = (const float*)d_in[14];
  const float* ff_b1  = (const float*)d_in[15];
  const float* ff_w2  = (const float*)d_in[16];
  const float* ff_b2  = (const float*)d_in[17];
  const float* head_r = (const float*)d_in[18];
  const float* last_w = (const float*)d_in[19];
  const float* last_b = (const float*)d_in[20];

  // workspace layout (floats): flags/embt/ycond/kvc/hq/xpart/xc2p/logitb/o_wT | kvhist | w2T
  const size_t baseFloats = 4096 + (size_t)NCLS*DM + (size_t)TT*DM
                          + (size_t)LAYERS*WIN*2*DM + DM + 2*8*DM + 8*DM + NCLS
                          + (size_t)LAYERS*DM*DM;                 // = 2,769,664
  const size_t histFloats = (size_t)LAYERS*TT*KVROW;              // = 4,325,376
  const size_t w2tFloats  = (size_t)LAYERS*GRID*8*DM;             // = 8,388,608
  const size_t needHist   = (baseFloats + histFloats) * sizeof(float);
  const size_t needW2T    = (baseFloats + histFloats + w2tFloats) * sizeof(float);
  float* kvhist = (ws_size >= needHist) ? ((float*)d_ws + baseFloats) : nullptr;
  float* w2T    = (ws_size >= needW2T)  ? ((float*)d_ws + baseFloats + histFloats) : nullptr;

  wf_kernel<<<GRID, BLK, 0, stream>>>(y, samp, emb, condW, ln_w, ln_b, kv_w, kv_b,
                                      q_w, q_b, o_w, o_b, fln_w, fln_b,
                                      ff_w1, ff_b1, ff_w2, ff_b2, head_r,
                                      last_w, last_b,
                                      (int*)d_out, (float*)d_ws, kvhist, w2T);
}